// Round 7
// baseline (123.776 us; speedup 1.0000x reference)
//
#include <hip/hip_runtime.h>
#include <hip/hip_fp16.h>

#define N_NODES 100000
#define N_FEAT  128
#define N_EDGES 1600000
#define OVF_CAP 65536

constexpr size_t align_up(size_t x) { return (x + 255) & ~size_t(255); }

// ================= tier 1: bucket-partition + LDS-sort + register agg ======
#define NBUCK   1563          // ceil(N_NODES / 64)
#define BCAP    1280          // mean 1024, +8 sigma
#define CHUNK   8192
#define NBLK_A  ((N_EDGES + CHUNK - 1) / CHUNK)   // 196
#define CONVBLK 2048
#define NCONV   (N_NODES * N_FEAT / 4)            // 3.2M float4
#define NXH     (N_NODES * 64)                    // u32 entries of fp16 x

constexpr size_t P_GCUR = 0;                                     // NBUCK ints (zeroed)
constexpr size_t P_DEGX = P_GCUR + align_up(NBUCK * 4);          // N floats (zeroed)
constexpr size_t P_OVFC = P_DEGX + align_up(N_NODES * 4);        // 1 int (zeroed)
constexpr size_t P_INV  = P_OVFC + 256;                          // N floats
constexpr size_t P_OVF  = P_INV  + align_up(N_NODES * 4);        // OVF_CAP*12
constexpr size_t P_XH   = P_OVF  + align_up(OVF_CAP * 12);       // NXH u32 (fp16 x, pair layout)
constexpr size_t P_BKT  = P_XH   + align_up((size_t)NXH * 4);    // NBUCK*BCAP u64
constexpr size_t WS_P   = P_BKT  + (size_t)NBUCK * BCAP * 8;     // ~43.3 MB
constexpr size_t P_ZERO = P_OVFC + 256;

// Kernel A: blocks [0, NBLK_A) partition edges into 64-node buckets;
//           blocks [NBLK_A, ...) convert x fp32 -> fp16 pair layout:
//           xh[n*64 + j] = half2(x[n][2j], x[n][2j+1])
__global__ __launch_bounds__(256) void k_part_conv(
    const int* __restrict__ src, const int* __restrict__ dst,
    const float* __restrict__ w, const float* __restrict__ x,
    uint2* __restrict__ xh_u2,
    int* __restrict__ gcur, unsigned long long* __restrict__ bucket,
    float* __restrict__ degx, int* __restrict__ ovf_cnt, int* __restrict__ ovf) {
    int tid = threadIdx.x;
    if (blockIdx.x >= NBLK_A) {
        // ---- conversion path (grid-stride over float4s) ----
        const float4* x4 = (const float4*)x;
        int stride = (gridDim.x - NBLK_A) * 256;
        for (int g = (blockIdx.x - NBLK_A) * 256 + tid; g < NCONV; g += stride) {
            float4 v = x4[g];
            __half2 h0 = __floats2half2_rn(v.x, v.y);
            __half2 h1 = __floats2half2_rn(v.z, v.w);
            uint2 u;
            __builtin_memcpy(&u.x, &h0, 4);
            __builtin_memcpy(&u.y, &h1, 4);
            xh_u2[g] = u;
        }
        return;
    }
    // ---- partition path ----
    __shared__ int hist[NBUCK];
    __shared__ int cbase[NBUCK];
    int e0 = blockIdx.x * CHUNK;
    int e1 = min(e0 + CHUNK, N_EDGES);

    for (int i = tid; i < NBUCK; i += 256) hist[i] = 0;
    __syncthreads();
    for (int e = e0 + tid; e < e1; e += 256)
        atomicAdd(&hist[src[e] >> 6], 1);
    __syncthreads();
    for (int i = tid; i < NBUCK; i += 256) {
        int c = hist[i];
        cbase[i] = c ? atomicAdd(&gcur[i], c) : 0;
        hist[i] = 0;              // reuse as local running cursor
    }
    __syncthreads();
    for (int e = e0 + tid; e < e1; e += 256) {
        int   s  = src[e];
        int   d  = dst[e];
        float ww = w[e];
        int k  = s >> 6;
        int ln = s & 63;
        int pos = cbase[k] + atomicAdd(&hist[k], 1);
        if (pos < BCAP) {
            unsigned hi = ((unsigned)ln << 17) | (unsigned)d;   // dst<2^17, ln 6b
            unsigned long long pk = ((unsigned long long)hi << 32) | __float_as_uint(ww);
            bucket[(size_t)k * BCAP + pos] = pk;
        } else {
            atomicAdd(&degx[s], ww);
            int o = atomicAdd(ovf_cnt, 1);
            if (o < OVF_CAP) { ovf[o*3] = s; ovf[o*3+1] = d; ovf[o*3+2] = __float_as_int(ww); }
        }
    }
}

// Kernel B: one block per bucket, 512 threads = 8 waves. In-LDS counting sort
// (bucket read twice from global: histogram pass, then scatter pass), then
// each wave register-aggregates 8 nodes.
__global__ __launch_bounds__(512) void k_bagg(
    const int* __restrict__ gcur, const unsigned long long* __restrict__ bucket,
    const unsigned* __restrict__ xh_u, const float* __restrict__ degx,
    float* __restrict__ inv_arr, float2* __restrict__ out2) {
    __shared__ uint2 sbuf[BCAP];    // node-sorted edges (10.25 KB)
    __shared__ int hist[64];
    __shared__ int rowo[64];
    __shared__ int curo[64];

    int bk   = blockIdx.x;
    int tid  = threadIdx.x;
    int lane = tid & 63;
    int wv   = tid >> 6;            // 0..7
    int n0   = bk * 64;
    int cnt  = min(gcur[bk], BCAP);

    if (tid < 64) { hist[tid] = 0; curo[tid] = 0; }
    __syncthreads();

    // pass 1: histogram (coalesced global read)
    for (int i = tid; i < cnt; i += 512) {
        unsigned hi = (unsigned)(bucket[(size_t)bk * BCAP + i] >> 32);
        atomicAdd(&hist[(hi >> 17) & 63], 1);
    }
    __syncthreads();

    // exclusive prefix scan over 64 counts (wave 0)
    if (tid < 64) {
        int v = hist[tid];
        int sc = v;
        #pragma unroll
        for (int off = 1; off < 64; off <<= 1) {
            int t = __shfl_up(sc, off);
            if (lane >= off) sc += t;
        }
        rowo[tid] = sc - v;
    }
    __syncthreads();

    // pass 2: scatter into node-sorted LDS (global re-read is L2-hot)
    for (int i = tid; i < cnt; i += 512) {
        unsigned long long ev = bucket[(size_t)bk * BCAP + i];
        uint2 e; e.x = (unsigned)ev; e.y = (unsigned)(ev >> 32);
        int ln = (e.y >> 17) & 63;
        int pos = rowo[ln] + atomicAdd(&curo[ln], 1);
        sbuf[pos] = e;
    }
    __syncthreads();

    // 8 waves x 8 nodes: register aggregation
    for (int i = 0; i < 8; ++i) {
        int n    = wv * 8 + i;
        int node = n0 + n;
        if (node >= N_NODES) break;
        int c = hist[n];
        int r = rowo[n];

        unsigned us = xh_u[(size_t)node * 64 + lane];   // self-loop, weight 1
        __half2 hs; __builtin_memcpy(&hs, &us, 4);
        float2 acc = __half22float2(hs);
        float wlane = 0.0f;

        for (int base = 0; base < c; base += 64) {
            int idx = base + lane;
            uint2 e = make_uint2(0u, 0u);
            if (idx < c) e = sbuf[r + idx];
            float ew = __uint_as_float(e.x);
            int   ed = (int)(e.y & 0x1FFFFu);
            wlane += ew;
            int m = min(64, c - base);
            int j = 0;
            for (; j + 7 < m; j += 8) {
                float ww[8]; float2 vv[8];
                #pragma unroll
                for (int q = 0; q < 8; ++q) {
                    float w8 = __shfl(ew, j + q);
                    int   d8 = __shfl(ed, j + q);
                    unsigned u = xh_u[(size_t)d8 * 64 + lane];
                    __half2 h; __builtin_memcpy(&h, &u, 4);
                    vv[q] = __half22float2(h);
                    ww[q] = w8;
                }
                #pragma unroll
                for (int q = 0; q < 8; ++q) { acc.x += ww[q]*vv[q].x; acc.y += ww[q]*vv[q].y; }
            }
            for (; j < m; ++j) {
                float w1 = __shfl(ew, j);
                int   d1 = __shfl(ed, j);
                unsigned u = xh_u[(size_t)d1 * 64 + lane];
                __half2 h; __builtin_memcpy(&h, &u, 4);
                float2 v = __half22float2(h);
                acc.x += w1 * v.x; acc.y += w1 * v.y;
            }
        }
        float ws = wlane;
        #pragma unroll
        for (int off = 1; off < 64; off <<= 1) ws += __shfl_xor(ws, off);
        float deg = 1.0f + ws + degx[node];
        float inv = 1.0f / fmaxf(deg, 1.0f);
        if (lane == 0) inv_arr[node] = inv;
        out2[(size_t)node * 64 + lane] = make_float2(acc.x * inv, acc.y * inv);
    }
}

__global__ void k_ovf(const int* __restrict__ ovf_cnt, const int* __restrict__ ovf,
                      const float* __restrict__ inv_arr,
                      const float* __restrict__ x, float* __restrict__ out) {
    int n = min(*ovf_cnt, OVF_CAP);
    for (int i = blockIdx.x * blockDim.x + threadIdx.x; i < n;
         i += gridDim.x * blockDim.x) {
        int s = ovf[i*3], d = ovf[i*3+1];
        float sc = __int_as_float(ovf[i*3+2]) * inv_arr[s];
        for (int f = 0; f < N_FEAT; ++f)
            atomicAdd(&out[(size_t)s * N_FEAT + f], sc * x[(size_t)d * N_FEAT + f]);
    }
}

// ================= tier 2: fp32 slot path (SLOTS=64, ~53.2 MB) =====
#define SLOTS_F 64
constexpr size_t G_CUR  = 0;
constexpr size_t G_DEGX = G_CUR  + align_up(N_NODES * 4);
constexpr size_t G_OVFC = G_DEGX + align_up(N_NODES * 4);
constexpr size_t G_INV  = G_OVFC + 256;
constexpr size_t G_OVF  = G_INV  + align_up(N_NODES * 4);
constexpr size_t G_SLOT = G_OVF  + align_up(OVF_CAP * 12);
constexpr size_t WS_G   = G_SLOT + (size_t)N_NODES * SLOTS_F * 8;
constexpr size_t G_ZERO = G_OVFC + 256;

__global__ void g_build(const int* __restrict__ src, const int* __restrict__ dst,
                        const float* __restrict__ w,
                        int* __restrict__ cursor, uint2* __restrict__ slots,
                        float* __restrict__ degx,
                        int* __restrict__ ovf_cnt, int* __restrict__ ovf) {
    int e = blockIdx.x * blockDim.x + threadIdx.x;
    if (e >= N_EDGES) return;
    int s = src[e], d = dst[e];
    float ww = w[e];
    int c = atomicAdd(&cursor[s], 1);
    if (c < SLOTS_F) {
        uint2 v; v.x = (unsigned)d; v.y = __float_as_uint(ww);
        slots[(size_t)s * SLOTS_F + c] = v;
    } else {
        atomicAdd(&degx[s], ww);
        int o = atomicAdd(ovf_cnt, 1);
        if (o < OVF_CAP) { ovf[o*3] = s; ovf[o*3+1] = d; ovf[o*3+2] = __float_as_int(ww); }
    }
}

__global__ __launch_bounds__(256) void g_agg(
    const int* __restrict__ cursor, const uint2* __restrict__ slots,
    const float* __restrict__ degx, float* __restrict__ inv_arr,
    const float2* __restrict__ x2, float2* __restrict__ out2) {
    int wid  = (int)((blockIdx.x * (long long)blockDim.x + threadIdx.x) >> 6);
    int lane = threadIdx.x & 63;
    if (wid >= N_NODES) return;
    int c = min(cursor[wid], SLOTS_F);
    int dv = 0; float wv = 0.0f;
    if (lane < c) {
        uint2 sl = slots[(size_t)wid * SLOTS_F + lane];
        dv = (int)sl.x; wv = __uint_as_float(sl.y);
    }
    float wsum = wv;
    #pragma unroll
    for (int off = 1; off < 64; off <<= 1) wsum += __shfl_xor(wsum, off);
    float deg = 1.0f + wsum + degx[wid];
    float inv = 1.0f / fmaxf(deg, 1.0f);
    if (lane == 0) inv_arr[wid] = inv;
    float2 acc = x2[(size_t)wid * 64 + lane];
    int k = 0;
    for (; k + 3 < c; k += 4) {
        int   d0 = __shfl(dv, k),   d1 = __shfl(dv, k+1);
        int   d2 = __shfl(dv, k+2), d3 = __shfl(dv, k+3);
        float w0 = __shfl(wv, k),   w1 = __shfl(wv, k+1);
        float w2 = __shfl(wv, k+2), w3 = __shfl(wv, k+3);
        float2 v0 = x2[(size_t)d0 * 64 + lane];
        float2 v1 = x2[(size_t)d1 * 64 + lane];
        float2 v2 = x2[(size_t)d2 * 64 + lane];
        float2 v3 = x2[(size_t)d3 * 64 + lane];
        acc.x += w0*v0.x + w1*v1.x + w2*v2.x + w3*v3.x;
        acc.y += w0*v0.y + w1*v1.y + w2*v2.y + w3*v3.y;
    }
    for (; k < c; ++k) {
        int d = __shfl(dv, k); float w = __shfl(wv, k);
        float2 v = x2[(size_t)d * 64 + lane];
        acc.x += w * v.x; acc.y += w * v.y;
    }
    out2[(size_t)wid * 64 + lane] = make_float2(acc.x * inv, acc.y * inv);
}

// ================= tier 3: CSR path (~14.4 MB) =================
constexpr size_t F_CNT = 0;
constexpr size_t F_ROW = F_CNT + align_up(N_NODES * 4);
constexpr size_t F_CUR = F_ROW + align_up(N_NODES * 4);
constexpr size_t F_DEG = F_CUR + align_up(N_NODES * 4);
constexpr size_t F_TOT = F_DEG + align_up(N_NODES * 4);
constexpr size_t F_DST = F_TOT + 256;
constexpr size_t F_W   = F_DST + align_up(N_EDGES * 4);
constexpr size_t WS_CSR = F_W + N_EDGES * 4;

__global__ void c_init(int* cnt, float* deg, int* total) {
    int i = blockIdx.x * blockDim.x + threadIdx.x;
    if (i < N_NODES) { cnt[i] = 0; deg[i] = 1.0f; }
    if (i == 0) *total = 0;
}
__global__ void c_count(const int* src, const float* w, int* cnt, float* deg) {
    int e = blockIdx.x * blockDim.x + threadIdx.x;
    if (e < N_EDGES) { int s = src[e]; atomicAdd(&cnt[s], 1); atomicAdd(&deg[s], w[e]); }
}
__global__ void c_alloc(const int* cnt, int* rowstart, int* cursor, float* deg, int* total) {
    int i = blockIdx.x * blockDim.x + threadIdx.x;
    if (i < N_NODES) {
        int c = cnt[i]; int s = atomicAdd(total, c);
        rowstart[i] = s; cursor[i] = s;
        deg[i] = 1.0f / fmaxf(deg[i], 1.0f);
    }
}
__global__ void c_scatter(const int* src, const int* dst, const float* w,
                          int* cursor, int* csr_dst, float* csr_w) {
    int e = blockIdx.x * blockDim.x + threadIdx.x;
    if (e < N_EDGES) {
        int pos = atomicAdd(&cursor[src[e]], 1);
        csr_dst[pos] = dst[e]; csr_w[pos] = w[e];
    }
}
__global__ __launch_bounds__(256) void c_agg(
    const int* rowstart, const int* cnt, const float* inv,
    const int* csr_dst, const float* csr_w,
    const float2* x2, float2* out2) {
    int wid  = (int)((blockIdx.x * (long long)blockDim.x + threadIdx.x) >> 6);
    int lane = threadIdx.x & 63;
    if (wid >= N_NODES) return;
    int s = rowstart[wid], c = cnt[wid];
    float2 acc = x2[(size_t)wid * 64 + lane];
    for (int base = 0; base < c; base += 64) {
        int dv = 0; float wv = 0.0f;
        int idx = base + lane;
        if (idx < c) { dv = csr_dst[s + idx]; wv = csr_w[s + idx]; }
        int m = min(64, c - base);
        for (int k = 0; k < m; ++k) {
            int d = __shfl(dv, k); float w = __shfl(wv, k);
            float2 v = x2[(size_t)d * 64 + lane];
            acc.x += w * v.x; acc.y += w * v.y;
        }
    }
    float si = inv[wid];
    out2[(size_t)wid * 64 + lane] = make_float2(acc.x * si, acc.y * si);
}

// ================= tier 4: atomic fallback =================
__global__ void fb_init_deg(float* deg) {
    int i = blockIdx.x * blockDim.x + threadIdx.x;
    if (i < N_NODES) deg[i] = 1.0f;
}
__global__ void fb_accum_deg(const int* src, const float* w, float* deg) {
    int e = blockIdx.x * blockDim.x + threadIdx.x;
    if (e < N_EDGES) atomicAdd(&deg[src[e]], w[e]);
}
__global__ void fb_inv_deg(float* deg) {
    int i = blockIdx.x * blockDim.x + threadIdx.x;
    if (i < N_NODES) deg[i] = 1.0f / fmaxf(deg[i], 1.0f);
}
__global__ void fb_self(const float4* x4, const float* inv, float4* out4) {
    int idx = blockIdx.x * blockDim.x + threadIdx.x;
    if (idx < N_NODES * (N_FEAT / 4)) {
        int node = idx >> 5; float s = inv[node];
        float4 v = x4[idx];
        out4[idx] = make_float4(v.x*s, v.y*s, v.z*s, v.w*s);
    }
}
__global__ void fb_edges(const int* src, const int* dst, const float* w,
                         const float* inv, const float4* x4, float* out) {
    long long gid = (long long)blockIdx.x * blockDim.x + threadIdx.x;
    int e = (int)(gid >> 5); int lane = (int)(gid & 31);
    if (e < N_EDGES) {
        int s = src[e];
        float sc = w[e] * inv[s];
        float4 v = x4[(long long)dst[e] * (N_FEAT/4) + lane];
        float* ob = out + (long long)s * N_FEAT + lane * 4;
        atomicAdd(ob+0, sc*v.x); atomicAdd(ob+1, sc*v.y);
        atomicAdd(ob+2, sc*v.z); atomicAdd(ob+3, sc*v.w);
    }
}

extern "C" void kernel_launch(void* const* d_in, const int* in_sizes, int n_in,
                              void* d_out, int out_size, void* d_ws, size_t ws_size,
                              hipStream_t stream) {
    const float* x          = (const float*)d_in[0];
    const int*   edge_index = (const int*)d_in[1];   // (2, E) row-major
    const float* edge_w     = (const float*)d_in[2];
    const int* src = edge_index;
    const int* dst = edge_index + N_EDGES;
    float* out = (float*)d_out;
    const int B = 256;

    if (ws_size >= WS_P) {
        char* ws = (char*)d_ws;
        int*      gcur    = (int*)     (ws + P_GCUR);
        float*    degx    = (float*)   (ws + P_DEGX);
        int*      ovf_cnt = (int*)     (ws + P_OVFC);
        float*    inv_arr = (float*)   (ws + P_INV);
        int*      ovf     = (int*)     (ws + P_OVF);
        uint2*    xh_u2   = (uint2*)   (ws + P_XH);
        unsigned* xh_u    = (unsigned*)(ws + P_XH);
        unsigned long long* bucket = (unsigned long long*)(ws + P_BKT);

        hipMemsetAsync(d_ws, 0, P_ZERO, stream);
        k_part_conv<<<NBLK_A + CONVBLK, 256, 0, stream>>>(
            src, dst, edge_w, x, xh_u2, gcur, bucket, degx, ovf_cnt, ovf);
        k_bagg<<<NBUCK, 512, 0, stream>>>(
            gcur, bucket, xh_u, degx, inv_arr, (float2*)out);
        k_ovf<<<32, 256, 0, stream>>>(ovf_cnt, ovf, inv_arr, x, out);
        return;
    }

    if (ws_size >= WS_G) {
        char* ws = (char*)d_ws;
        int*   cursor  = (int*)  (ws + G_CUR);
        float* degx    = (float*)(ws + G_DEGX);
        int*   ovf_cnt = (int*)  (ws + G_OVFC);
        float* inv_arr = (float*)(ws + G_INV);
        int*   ovf     = (int*)  (ws + G_OVF);
        uint2* slots   = (uint2*)(ws + G_SLOT);
        hipMemsetAsync(d_ws, 0, G_ZERO, stream);
        g_build<<<(N_EDGES + B - 1) / B, B, 0, stream>>>(
            src, dst, edge_w, cursor, slots, degx, ovf_cnt, ovf);
        long long t_agg = (long long)N_NODES * 64;
        g_agg<<<(int)((t_agg + B - 1) / B), B, 0, stream>>>(
            cursor, slots, degx, inv_arr, (const float2*)x, (float2*)out);
        k_ovf<<<32, 256, 0, stream>>>(ovf_cnt, ovf, inv_arr, x, out);
        return;
    }

    if (ws_size >= WS_CSR) {
        char* ws = (char*)d_ws;
        int*   cnt      = (int*)  (ws + F_CNT);
        int*   rowstart = (int*)  (ws + F_ROW);
        int*   cursor   = (int*)  (ws + F_CUR);
        float* deg      = (float*)(ws + F_DEG);
        int*   total    = (int*)  (ws + F_TOT);
        int*   csr_dst  = (int*)  (ws + F_DST);
        float* csr_w    = (float*)(ws + F_W);
        c_init<<<(N_NODES + B - 1) / B, B, 0, stream>>>(cnt, deg, total);
        c_count<<<(N_EDGES + B - 1) / B, B, 0, stream>>>(src, edge_w, cnt, deg);
        c_alloc<<<(N_NODES + B - 1) / B, B, 0, stream>>>(cnt, rowstart, cursor, deg, total);
        c_scatter<<<(N_EDGES + B - 1) / B, B, 0, stream>>>(src, dst, edge_w, cursor,
                                                           csr_dst, csr_w);
        long long t_agg = (long long)N_NODES * 64;
        c_agg<<<(int)((t_agg + B - 1) / B), B, 0, stream>>>(
            rowstart, cnt, deg, csr_dst, csr_w, (const float2*)x, (float2*)out);
        return;
    }

    float* deg = (float*)d_ws;
    fb_init_deg<<<(N_NODES + B - 1) / B, B, 0, stream>>>(deg);
    fb_accum_deg<<<(N_EDGES + B - 1) / B, B, 0, stream>>>(src, edge_w, deg);
    fb_inv_deg<<<(N_NODES + B - 1) / B, B, 0, stream>>>(deg);
    int n4 = N_NODES * (N_FEAT / 4);
    fb_self<<<(n4 + B - 1) / B, B, 0, stream>>>((const float4*)x, deg, (float4*)out);
    long long total = (long long)N_EDGES * 32;
    fb_edges<<<(int)((total + B - 1) / B), B, 0, stream>>>(
        src, dst, edge_w, deg, (const float4*)x, out);
}

// Round 8
// 113.851 us; speedup vs baseline: 1.0872x; 1.0872x over previous
//
#include <hip/hip_runtime.h>
#include <hip/hip_fp16.h>

#define N_NODES 100000
#define N_FEAT  128
#define N_EDGES 1600000
#define OVF_CAP 65536

constexpr size_t align_up(size_t x) { return (x + 255) & ~size_t(255); }

// ================= tier 1: bucket-partition + LDS-sort + paired register agg
#define NBUCK   1563          // ceil(N_NODES / 64)
#define BCAP    1280          // mean 1024, +8 sigma
#define CHUNK   8192
#define NBLK_A  ((N_EDGES + CHUNK - 1) / CHUNK)   // 196
#define CONVBLK 2048
#define NCONV   (N_NODES * N_FEAT / 4)            // 3.2M float4 == N*32 uint2
#define NXH     (N_NODES * 64)                    // u32 entries of fp16 x

constexpr size_t P_GCUR = 0;                                     // NBUCK ints (zeroed)
constexpr size_t P_DEGX = P_GCUR + align_up(NBUCK * 4);          // N floats (zeroed)
constexpr size_t P_OVFC = P_DEGX + align_up(N_NODES * 4);        // 1 int (zeroed)
constexpr size_t P_INV  = P_OVFC + 256;                          // N floats
constexpr size_t P_OVF  = P_INV  + align_up(N_NODES * 4);        // OVF_CAP*12
constexpr size_t P_XH   = P_OVF  + align_up(OVF_CAP * 12);       // NXH u32 (fp16 x)
constexpr size_t P_BKT  = P_XH   + align_up((size_t)NXH * 4);    // NBUCK*BCAP u64
constexpr size_t WS_P   = P_BKT  + (size_t)NBUCK * BCAP * 8;     // ~43.3 MB
constexpr size_t P_ZERO = P_OVFC + 256;

// Kernel A: blocks [0, NBLK_A) partition edges into 64-node buckets;
//           blocks [NBLK_A, ...) convert x fp32 -> fp16:
//           xh2[n*32 + l] = {half2(x[n][4l],x[n][4l+1]), half2(x[n][4l+2],x[n][4l+3])}
__global__ __launch_bounds__(256) void k_part_conv(
    const int* __restrict__ src, const int* __restrict__ dst,
    const float* __restrict__ w, const float* __restrict__ x,
    uint2* __restrict__ xh_u2,
    int* __restrict__ gcur, unsigned long long* __restrict__ bucket,
    float* __restrict__ degx, int* __restrict__ ovf_cnt, int* __restrict__ ovf) {
    int tid = threadIdx.x;
    if (blockIdx.x >= NBLK_A) {
        const float4* x4 = (const float4*)x;
        int stride = (gridDim.x - NBLK_A) * 256;
        for (int g = (blockIdx.x - NBLK_A) * 256 + tid; g < NCONV; g += stride) {
            float4 v = x4[g];
            __half2 h0 = __floats2half2_rn(v.x, v.y);
            __half2 h1 = __floats2half2_rn(v.z, v.w);
            uint2 u;
            __builtin_memcpy(&u.x, &h0, 4);
            __builtin_memcpy(&u.y, &h1, 4);
            xh_u2[g] = u;
        }
        return;
    }
    __shared__ int hist[NBUCK];
    __shared__ int cbase[NBUCK];
    int e0 = blockIdx.x * CHUNK;
    int e1 = min(e0 + CHUNK, N_EDGES);

    for (int i = tid; i < NBUCK; i += 256) hist[i] = 0;
    __syncthreads();
    for (int e = e0 + tid; e < e1; e += 256)
        atomicAdd(&hist[src[e] >> 6], 1);
    __syncthreads();
    for (int i = tid; i < NBUCK; i += 256) {
        int c = hist[i];
        cbase[i] = c ? atomicAdd(&gcur[i], c) : 0;
        hist[i] = 0;              // reuse as local running cursor
    }
    __syncthreads();
    for (int e = e0 + tid; e < e1; e += 256) {
        int   s  = src[e];
        int   d  = dst[e];
        float ww = w[e];
        int k  = s >> 6;
        int ln = s & 63;
        int pos = cbase[k] + atomicAdd(&hist[k], 1);
        if (pos < BCAP) {
            unsigned hi = ((unsigned)ln << 17) | (unsigned)d;   // dst<2^17, ln 6b
            unsigned long long pk = ((unsigned long long)hi << 32) | __float_as_uint(ww);
            bucket[(size_t)k * BCAP + pos] = pk;
        } else {
            atomicAdd(&degx[s], ww);
            int o = atomicAdd(ovf_cnt, 1);
            if (o < OVF_CAP) { ovf[o*3] = s; ovf[o*3+1] = d; ovf[o*3+2] = __float_as_int(ww); }
        }
    }
}

// Kernel B: one block per bucket, 512 threads = 8 waves. Bucket edges held in
// registers (single global read) -> LDS histogram -> scan -> scatter to
// node-sorted sbuf. Agg: each wave owns 8 nodes; per iteration the wave
// processes TWO edges (lanes 0-31 edge j, lanes 32-63 edge j+1), each lane
// gathering 8 B (4 feats); halves folded by shfl_xor(32) at the end.
__global__ __launch_bounds__(512) void k_bagg(
    const int* __restrict__ gcur, const unsigned long long* __restrict__ bucket,
    const uint2* __restrict__ xh2, const float* __restrict__ degx,
    float* __restrict__ inv_arr, float4* __restrict__ out4) {
    __shared__ uint2 sbuf[BCAP];    // node-sorted edges (10.25 KB)
    __shared__ int hist[64];
    __shared__ int rowo[64];
    __shared__ int curo[64];

    int bk   = blockIdx.x;
    int tid  = threadIdx.x;
    int lane = tid & 63;
    int wv   = tid >> 6;            // 0..7
    int h    = lane >> 5;           // half: 0 or 1
    int il   = lane & 31;
    int n0   = bk * 64;
    int cnt  = min(gcur[bk], BCAP);

    if (tid < 64) { hist[tid] = 0; curo[tid] = 0; }
    __syncthreads();

    // single global read of the bucket into named registers
    uint2 er0 = make_uint2(0u, 0u), er1 = er0, er2 = er0;
    {
        const uint2* bsrc = (const uint2*)(bucket + (size_t)bk * BCAP);
        if (tid < cnt)        er0 = bsrc[tid];
        if (tid + 512 < cnt)  er1 = bsrc[tid + 512];
        if (tid + 1024 < cnt) er2 = bsrc[tid + 1024];
    }
    // histogram
    if (tid < cnt)        atomicAdd(&hist[(er0.y >> 17) & 63], 1);
    if (tid + 512 < cnt)  atomicAdd(&hist[(er1.y >> 17) & 63], 1);
    if (tid + 1024 < cnt) atomicAdd(&hist[(er2.y >> 17) & 63], 1);
    __syncthreads();

    // exclusive prefix scan over 64 counts (wave 0)
    if (tid < 64) {
        int v = hist[tid];
        int sc = v;
        #pragma unroll
        for (int off = 1; off < 64; off <<= 1) {
            int t = __shfl_up(sc, off);
            if (lane >= off) sc += t;
        }
        rowo[tid] = sc - v;
    }
    __syncthreads();

    // scatter into node-sorted LDS
    if (tid < cnt) {
        int ln = (er0.y >> 17) & 63;
        sbuf[rowo[ln] + atomicAdd(&curo[ln], 1)] = er0;
    }
    if (tid + 512 < cnt) {
        int ln = (er1.y >> 17) & 63;
        sbuf[rowo[ln] + atomicAdd(&curo[ln], 1)] = er1;
    }
    if (tid + 1024 < cnt) {
        int ln = (er2.y >> 17) & 63;
        sbuf[rowo[ln] + atomicAdd(&curo[ln], 1)] = er2;
    }
    __syncthreads();

    // 8 waves x 8 nodes: paired register aggregation
    for (int i = 0; i < 8; ++i) {
        int n    = wv * 8 + i;
        int node = n0 + n;
        if (node >= N_NODES) break;
        int c = hist[n];
        int r = rowo[n];

        // self-loop (weight 1): lower half holds it, upper half starts at 0
        float4 acc = make_float4(0.f, 0.f, 0.f, 0.f);
        if (h == 0) {
            uint2 u = xh2[(size_t)node * 32 + il];
            __half2 ha, hb;
            __builtin_memcpy(&ha, &u.x, 4);
            __builtin_memcpy(&hb, &u.y, 4);
            float2 va = __half22float2(ha), vb = __half22float2(hb);
            acc = make_float4(va.x, va.y, vb.x, vb.y);
        }
        float wdeg = 0.0f;

        for (int j = 0; j < c; j += 8) {
            float ews[4]; uint2 vs[4];
            #pragma unroll
            for (int p = 0; p < 4; ++p) {
                int idx = j + 2 * p + h;
                bool ok = idx < c;
                uint2 e = sbuf[r + (ok ? idx : 0)];
                ews[p] = ok ? __uint_as_float(e.x) : 0.0f;
                int ed = (int)(e.y & 0x1FFFFu);
                vs[p] = xh2[(size_t)ed * 32 + il];   // 8 B gather
            }
            #pragma unroll
            for (int p = 0; p < 4; ++p) {
                __half2 ha, hb;
                __builtin_memcpy(&ha, &vs[p].x, 4);
                __builtin_memcpy(&hb, &vs[p].y, 4);
                float2 va = __half22float2(ha), vb = __half22float2(hb);
                float ew = ews[p];
                acc.x += ew * va.x; acc.y += ew * va.y;
                acc.z += ew * vb.x; acc.w += ew * vb.y;
                if (il == 0) wdeg += ew;
            }
        }
        // fold halves
        acc.x += __shfl_xor(acc.x, 32);
        acc.y += __shfl_xor(acc.y, 32);
        acc.z += __shfl_xor(acc.z, 32);
        acc.w += __shfl_xor(acc.w, 32);
        float ws = wdeg;
        #pragma unroll
        for (int off = 1; off < 64; off <<= 1) ws += __shfl_xor(ws, off);

        float deg = 1.0f + ws + degx[node];
        float inv = 1.0f / fmaxf(deg, 1.0f);
        if (lane == 0) inv_arr[node] = inv;
        if (h == 0)
            out4[(size_t)node * 32 + il] =
                make_float4(acc.x * inv, acc.y * inv, acc.z * inv, acc.w * inv);
    }
}

__global__ void k_ovf(const int* __restrict__ ovf_cnt, const int* __restrict__ ovf,
                      const float* __restrict__ inv_arr,
                      const float* __restrict__ x, float* __restrict__ out) {
    int n = min(*ovf_cnt, OVF_CAP);
    for (int i = blockIdx.x * blockDim.x + threadIdx.x; i < n;
         i += gridDim.x * blockDim.x) {
        int s = ovf[i*3], d = ovf[i*3+1];
        float sc = __int_as_float(ovf[i*3+2]) * inv_arr[s];
        for (int f = 0; f < N_FEAT; ++f)
            atomicAdd(&out[(size_t)s * N_FEAT + f], sc * x[(size_t)d * N_FEAT + f]);
    }
}

// ================= tier 2: fp32 slot path (SLOTS=64, ~53.2 MB) =====
#define SLOTS_F 64
constexpr size_t G_CUR  = 0;
constexpr size_t G_DEGX = G_CUR  + align_up(N_NODES * 4);
constexpr size_t G_OVFC = G_DEGX + align_up(N_NODES * 4);
constexpr size_t G_INV  = G_OVFC + 256;
constexpr size_t G_OVF  = G_INV  + align_up(N_NODES * 4);
constexpr size_t G_SLOT = G_OVF  + align_up(OVF_CAP * 12);
constexpr size_t WS_G   = G_SLOT + (size_t)N_NODES * SLOTS_F * 8;
constexpr size_t G_ZERO = G_OVFC + 256;

__global__ void g_build(const int* __restrict__ src, const int* __restrict__ dst,
                        const float* __restrict__ w,
                        int* __restrict__ cursor, uint2* __restrict__ slots,
                        float* __restrict__ degx,
                        int* __restrict__ ovf_cnt, int* __restrict__ ovf) {
    int e = blockIdx.x * blockDim.x + threadIdx.x;
    if (e >= N_EDGES) return;
    int s = src[e], d = dst[e];
    float ww = w[e];
    int c = atomicAdd(&cursor[s], 1);
    if (c < SLOTS_F) {
        uint2 v; v.x = (unsigned)d; v.y = __float_as_uint(ww);
        slots[(size_t)s * SLOTS_F + c] = v;
    } else {
        atomicAdd(&degx[s], ww);
        int o = atomicAdd(ovf_cnt, 1);
        if (o < OVF_CAP) { ovf[o*3] = s; ovf[o*3+1] = d; ovf[o*3+2] = __float_as_int(ww); }
    }
}

__global__ __launch_bounds__(256) void g_agg(
    const int* __restrict__ cursor, const uint2* __restrict__ slots,
    const float* __restrict__ degx, float* __restrict__ inv_arr,
    const float2* __restrict__ x2, float2* __restrict__ out2) {
    int wid  = (int)((blockIdx.x * (long long)blockDim.x + threadIdx.x) >> 6);
    int lane = threadIdx.x & 63;
    if (wid >= N_NODES) return;
    int c = min(cursor[wid], SLOTS_F);
    int dv = 0; float wv = 0.0f;
    if (lane < c) {
        uint2 sl = slots[(size_t)wid * SLOTS_F + lane];
        dv = (int)sl.x; wv = __uint_as_float(sl.y);
    }
    float wsum = wv;
    #pragma unroll
    for (int off = 1; off < 64; off <<= 1) wsum += __shfl_xor(wsum, off);
    float deg = 1.0f + wsum + degx[wid];
    float inv = 1.0f / fmaxf(deg, 1.0f);
    if (lane == 0) inv_arr[wid] = inv;
    float2 acc = x2[(size_t)wid * 64 + lane];
    int k = 0;
    for (; k + 3 < c; k += 4) {
        int   d0 = __shfl(dv, k),   d1 = __shfl(dv, k+1);
        int   d2 = __shfl(dv, k+2), d3 = __shfl(dv, k+3);
        float w0 = __shfl(wv, k),   w1 = __shfl(wv, k+1);
        float w2 = __shfl(wv, k+2), w3 = __shfl(wv, k+3);
        float2 v0 = x2[(size_t)d0 * 64 + lane];
        float2 v1 = x2[(size_t)d1 * 64 + lane];
        float2 v2 = x2[(size_t)d2 * 64 + lane];
        float2 v3 = x2[(size_t)d3 * 64 + lane];
        acc.x += w0*v0.x + w1*v1.x + w2*v2.x + w3*v3.x;
        acc.y += w0*v0.y + w1*v1.y + w2*v2.y + w3*v3.y;
    }
    for (; k < c; ++k) {
        int d = __shfl(dv, k); float w = __shfl(wv, k);
        float2 v = x2[(size_t)d * 64 + lane];
        acc.x += w * v.x; acc.y += w * v.y;
    }
    out2[(size_t)wid * 64 + lane] = make_float2(acc.x * inv, acc.y * inv);
}

// ================= tier 3: CSR path (~14.4 MB) =================
constexpr size_t F_CNT = 0;
constexpr size_t F_ROW = F_CNT + align_up(N_NODES * 4);
constexpr size_t F_CUR = F_ROW + align_up(N_NODES * 4);
constexpr size_t F_DEG = F_CUR + align_up(N_NODES * 4);
constexpr size_t F_TOT = F_DEG + align_up(N_NODES * 4);
constexpr size_t F_DST = F_TOT + 256;
constexpr size_t F_W   = F_DST + align_up(N_EDGES * 4);
constexpr size_t WS_CSR = F_W + N_EDGES * 4;

__global__ void c_init(int* cnt, float* deg, int* total) {
    int i = blockIdx.x * blockDim.x + threadIdx.x;
    if (i < N_NODES) { cnt[i] = 0; deg[i] = 1.0f; }
    if (i == 0) *total = 0;
}
__global__ void c_count(const int* src, const float* w, int* cnt, float* deg) {
    int e = blockIdx.x * blockDim.x + threadIdx.x;
    if (e < N_EDGES) { int s = src[e]; atomicAdd(&cnt[s], 1); atomicAdd(&deg[s], w[e]); }
}
__global__ void c_alloc(const int* cnt, int* rowstart, int* cursor, float* deg, int* total) {
    int i = blockIdx.x * blockDim.x + threadIdx.x;
    if (i < N_NODES) {
        int c = cnt[i]; int s = atomicAdd(total, c);
        rowstart[i] = s; cursor[i] = s;
        deg[i] = 1.0f / fmaxf(deg[i], 1.0f);
    }
}
__global__ void c_scatter(const int* src, const int* dst, const float* w,
                          int* cursor, int* csr_dst, float* csr_w) {
    int e = blockIdx.x * blockDim.x + threadIdx.x;
    if (e < N_EDGES) {
        int pos = atomicAdd(&cursor[src[e]], 1);
        csr_dst[pos] = dst[e]; csr_w[pos] = w[e];
    }
}
__global__ __launch_bounds__(256) void c_agg(
    const int* rowstart, const int* cnt, const float* inv,
    const int* csr_dst, const float* csr_w,
    const float2* x2, float2* out2) {
    int wid  = (int)((blockIdx.x * (long long)blockDim.x + threadIdx.x) >> 6);
    int lane = threadIdx.x & 63;
    if (wid >= N_NODES) return;
    int s = rowstart[wid], c = cnt[wid];
    float2 acc = x2[(size_t)wid * 64 + lane];
    for (int base = 0; base < c; base += 64) {
        int dv = 0; float wv = 0.0f;
        int idx = base + lane;
        if (idx < c) { dv = csr_dst[s + idx]; wv = csr_w[s + idx]; }
        int m = min(64, c - base);
        for (int k = 0; k < m; ++k) {
            int d = __shfl(dv, k); float w = __shfl(wv, k);
            float2 v = x2[(size_t)d * 64 + lane];
            acc.x += w * v.x; acc.y += w * v.y;
        }
    }
    float si = inv[wid];
    out2[(size_t)wid * 64 + lane] = make_float2(acc.x * si, acc.y * si);
}

// ================= tier 4: atomic fallback =================
__global__ void fb_init_deg(float* deg) {
    int i = blockIdx.x * blockDim.x + threadIdx.x;
    if (i < N_NODES) deg[i] = 1.0f;
}
__global__ void fb_accum_deg(const int* src, const float* w, float* deg) {
    int e = blockIdx.x * blockDim.x + threadIdx.x;
    if (e < N_EDGES) atomicAdd(&deg[src[e]], w[e]);
}
__global__ void fb_inv_deg(float* deg) {
    int i = blockIdx.x * blockDim.x + threadIdx.x;
    if (i < N_NODES) deg[i] = 1.0f / fmaxf(deg[i], 1.0f);
}
__global__ void fb_self(const float4* x4, const float* inv, float4* out4) {
    int idx = blockIdx.x * blockDim.x + threadIdx.x;
    if (idx < N_NODES * (N_FEAT / 4)) {
        int node = idx >> 5; float s = inv[node];
        float4 v = x4[idx];
        out4[idx] = make_float4(v.x*s, v.y*s, v.z*s, v.w*s);
    }
}
__global__ void fb_edges(const int* src, const int* dst, const float* w,
                         const float* inv, const float4* x4, float* out) {
    long long gid = (long long)blockIdx.x * blockDim.x + threadIdx.x;
    int e = (int)(gid >> 5); int lane = (int)(gid & 31);
    if (e < N_EDGES) {
        int s = src[e];
        float sc = w[e] * inv[s];
        float4 v = x4[(long long)dst[e] * (N_FEAT/4) + lane];
        float* ob = out + (long long)s * N_FEAT + lane * 4;
        atomicAdd(ob+0, sc*v.x); atomicAdd(ob+1, sc*v.y);
        atomicAdd(ob+2, sc*v.z); atomicAdd(ob+3, sc*v.w);
    }
}

extern "C" void kernel_launch(void* const* d_in, const int* in_sizes, int n_in,
                              void* d_out, int out_size, void* d_ws, size_t ws_size,
                              hipStream_t stream) {
    const float* x          = (const float*)d_in[0];
    const int*   edge_index = (const int*)d_in[1];   // (2, E) row-major
    const float* edge_w     = (const float*)d_in[2];
    const int* src = edge_index;
    const int* dst = edge_index + N_EDGES;
    float* out = (float*)d_out;
    const int B = 256;

    if (ws_size >= WS_P) {
        char* ws = (char*)d_ws;
        int*      gcur    = (int*)     (ws + P_GCUR);
        float*    degx    = (float*)   (ws + P_DEGX);
        int*      ovf_cnt = (int*)     (ws + P_OVFC);
        float*    inv_arr = (float*)   (ws + P_INV);
        int*      ovf     = (int*)     (ws + P_OVF);
        uint2*    xh_u2   = (uint2*)   (ws + P_XH);
        unsigned long long* bucket = (unsigned long long*)(ws + P_BKT);

        hipMemsetAsync(d_ws, 0, P_ZERO, stream);
        k_part_conv<<<NBLK_A + CONVBLK, 256, 0, stream>>>(
            src, dst, edge_w, x, xh_u2, gcur, bucket, degx, ovf_cnt, ovf);
        k_bagg<<<NBUCK, 512, 0, stream>>>(
            gcur, bucket, xh_u2, degx, inv_arr, (float4*)out);
        k_ovf<<<32, 256, 0, stream>>>(ovf_cnt, ovf, inv_arr, x, out);
        return;
    }

    if (ws_size >= WS_G) {
        char* ws = (char*)d_ws;
        int*   cursor  = (int*)  (ws + G_CUR);
        float* degx    = (float*)(ws + G_DEGX);
        int*   ovf_cnt = (int*)  (ws + G_OVFC);
        float* inv_arr = (float*)(ws + G_INV);
        int*   ovf     = (int*)  (ws + G_OVF);
        uint2* slots   = (uint2*)(ws + G_SLOT);
        hipMemsetAsync(d_ws, 0, G_ZERO, stream);
        g_build<<<(N_EDGES + B - 1) / B, B, 0, stream>>>(
            src, dst, edge_w, cursor, slots, degx, ovf_cnt, ovf);
        long long t_agg = (long long)N_NODES * 64;
        g_agg<<<(int)((t_agg + B - 1) / B), B, 0, stream>>>(
            cursor, slots, degx, inv_arr, (const float2*)x, (float2*)out);
        k_ovf<<<32, 256, 0, stream>>>(ovf_cnt, ovf, inv_arr, x, out);
        return;
    }

    if (ws_size >= WS_CSR) {
        char* ws = (char*)d_ws;
        int*   cnt      = (int*)  (ws + F_CNT);
        int*   rowstart = (int*)  (ws + F_ROW);
        int*   cursor   = (int*)  (ws + F_CUR);
        float* deg      = (float*)(ws + F_DEG);
        int*   total    = (int*)  (ws + F_TOT);
        int*   csr_dst  = (int*)  (ws + F_DST);
        float* csr_w    = (float*)(ws + F_W);
        c_init<<<(N_NODES + B - 1) / B, B, 0, stream>>>(cnt, deg, total);
        c_count<<<(N_EDGES + B - 1) / B, B, 0, stream>>>(src, edge_w, cnt, deg);
        c_alloc<<<(N_NODES + B - 1) / B, B, 0, stream>>>(cnt, rowstart, cursor, deg, total);
        c_scatter<<<(N_EDGES + B - 1) / B, B, 0, stream>>>(src, dst, edge_w, cursor,
                                                           csr_dst, csr_w);
        long long t_agg = (long long)N_NODES * 64;
        c_agg<<<(int)((t_agg + B - 1) / B), B, 0, stream>>>(
            rowstart, cnt, deg, csr_dst, csr_w, (const float2*)x, (float2*)out);
        return;
    }

    float* deg = (float*)d_ws;
    fb_init_deg<<<(N_NODES + B - 1) / B, B, 0, stream>>>(deg);
    fb_accum_deg<<<(N_EDGES + B - 1) / B, B, 0, stream>>>(src, edge_w, deg);
    fb_inv_deg<<<(N_NODES + B - 1) / B, B, 0, stream>>>(deg);
    int n4 = N_NODES * (N_FEAT / 4);
    fb_self<<<(n4 + B - 1) / B, B, 0, stream>>>((const float4*)x, deg, (float4*)out);
    long long total = (long long)N_EDGES * 32;
    fb_edges<<<(int)((total + B - 1) / B), B, 0, stream>>>(
        src, dst, edge_w, deg, (const float4*)x, out);
}